// Round 1
// baseline (127.486 us; speedup 1.0000x reference)
//
#include <hip/hip_runtime.h>

// MRConv1d: B=4, N=10000, C=128, K=16, OUT=128
// out[b,n,o] = relu( sum_c2 feat[b,n,c2]*W[o,c2] + bias[o] )
// feat[b,n,2c]   = x[b,n,c]
// feat[b,n,2c+1] = max_k( x[b, e0[b,n,k], c] - x[b, e1[b,n,k], c] )

#define Bn 4
#define Nn 10000
#define Cn 128
#define Kn 16
#define OUTn 128
#define Mn 16           // nodes per block
#define FPAD 8          // sfeat row pad in bf16 elems (keeps 16B alignment: 264*2=528=33*16)

typedef __attribute__((ext_vector_type(8))) short short8;
typedef __attribute__((ext_vector_type(4))) float floatx4;

__device__ __forceinline__ unsigned short f2bf(float f) {
    union { float f; unsigned u; } v; v.f = f;
    unsigned r = v.u + 0x7fffu + ((v.u >> 16) & 1u);   // RNE
    return (unsigned short)(r >> 16);
}

// Pack W [OUT, 2C] fp32 into bf16 B-fragments for mfma_f32_16x16x32_bf16.
// Fragment element: Wb[((tile*8 + step)*64 + lane)*8 + j] = bf16(W[o][c2])
//   with o = tile*16 + (lane&15), c2 = step*32 + (lane>>4)*8 + j.
__global__ __launch_bounds__(256) void build_wb(const float* __restrict__ W,
                                                unsigned short* __restrict__ Wb) {
    int tid = blockIdx.x * 256 + threadIdx.x;   // 0..4095
    int lane = tid & 63;
    int step = (tid >> 6) & 7;
    int tile = tid >> 9;
    int o = tile * 16 + (lane & 15);
    int quad = lane >> 4;
    unsigned short v[8];
#pragma unroll
    for (int j = 0; j < 8; ++j) {
        int c2 = step * 32 + quad * 8 + j;
        v[j] = f2bf(W[o * (2 * Cn) + c2]);
    }
    uint4 pk;
    pk.x = (unsigned)v[0] | ((unsigned)v[1] << 16);
    pk.y = (unsigned)v[2] | ((unsigned)v[3] << 16);
    pk.z = (unsigned)v[4] | ((unsigned)v[5] << 16);
    pk.w = (unsigned)v[6] | ((unsigned)v[7] << 16);
    *(uint4*)(Wb + (size_t)tid * 8) = pk;
}

__global__ __launch_bounds__(256) void mrconv_kernel(
    const float* __restrict__ x, const int* __restrict__ edge,
    const unsigned short* __restrict__ Wb, const float* __restrict__ bias,
    float* __restrict__ out)
{
    __shared__ unsigned short sfeat[Mn][2 * Cn + FPAD];  // bf16 feature tile, interleaved
    __shared__ int sidx[2][Mn][Kn];

    // XCD-aware mapping: batch b pinned to XCD slots {b, b+4} so each XCD's
    // 4MiB L2 only serves one 5.1MB batch slice of x.
    // grid = 2560: per batch 640 block-slots, 625 used.
    int bi = blockIdx.x;
    int slot = bi & 7;
    int b = slot & 3;
    int nb = (bi >> 3) * 2 + (slot >> 2);
    if (nb >= Nn / Mn) return;
    const int n0 = nb * Mn;
    const int gbase = b * Nn + n0;

    const int t = threadIdx.x;
    const int wv = t >> 6;      // wave 0..3
    const int lane = t & 63;

    // stage edge indices for the block's 16 nodes: 2*16*16 = 512 ints
    for (int i = t; i < 2 * Mn * Kn; i += 256) {
        int s = i >> 8;
        int m = (i >> 4) & 15;
        int k = i & 15;
        sidx[s][m][k] = edge[s * (Bn * Nn * Kn) + (gbase + m) * Kn + k];
    }
    __syncthreads();

    const float* xb = x + b * (Nn * Cn);

    // phase 1: gather + max-relative. One wave per node, lane covers 2 channels.
    for (int it = 0; it < 4; ++it) {
        int m = wv * 4 + it;
        const float2 xs = *(const float2*)(xb + (n0 + m) * Cn + 2 * lane);
        float r0 = -3.402823466e+38f, r1 = -3.402823466e+38f;
#pragma unroll
        for (int k = 0; k < Kn; ++k) {
            int jj = sidx[0][m][k];
            int ii = sidx[1][m][k];
            const float2 vj = *(const float2*)(xb + jj * Cn + 2 * lane);
            const float2 vi = *(const float2*)(xb + ii * Cn + 2 * lane);
            r0 = fmaxf(r0, vj.x - vi.x);
            r1 = fmaxf(r1, vj.y - vi.y);
        }
        // interleaved: feat[4l..4l+3] = {x_{2l}, rel_{2l}, x_{2l+1}, rel_{2l+1}}
        ushort4 pk;
        pk.x = f2bf(xs.x); pk.y = f2bf(r0);
        pk.z = f2bf(xs.y); pk.w = f2bf(r1);
        *(ushort4*)&sfeat[m][4 * lane] = pk;
    }
    __syncthreads();

    // phase 2: out_tile[16 nodes][128] = feat[16][256] @ Wt[256][128] via MFMA bf16.
    // Wave wv computes output tiles {2wv, 2wv+1} (o in [wv*32, wv*32+32)).
    const int m16 = lane & 15;
    const int quad = lane >> 4;
    floatx4 acc0 = {0.f, 0.f, 0.f, 0.f};
    floatx4 acc1 = {0.f, 0.f, 0.f, 0.f};
    const short8* wb8 = (const short8*)Wb;
    const int tile0 = 2 * wv, tile1 = 2 * wv + 1;
#pragma unroll
    for (int step = 0; step < 8; ++step) {
        // A frag: A[m=lane&15][k = quad*8 + j], k-base = step*32
        short8 a = *(const short8*)&sfeat[m16][step * 32 + quad * 8];
        short8 b0 = wb8[(tile0 * 8 + step) * 64 + lane];
        short8 b1 = wb8[(tile1 * 8 + step) * 64 + lane];
        acc0 = __builtin_amdgcn_mfma_f32_16x16x32_bf16(a, b0, acc0, 0, 0, 0);
        acc1 = __builtin_amdgcn_mfma_f32_16x16x32_bf16(a, b1, acc1, 0, 0, 0);
    }
    // C/D layout: col = lane&15, row = quad*4 + reg
    const int o0 = tile0 * 16 + m16;
    const int o1 = tile1 * 16 + m16;
    const float bb0 = bias[o0], bb1 = bias[o1];
#pragma unroll
    for (int r = 0; r < 4; ++r) {
        int g = gbase + quad * 4 + r;
        out[g * OUTn + o0] = fmaxf(acc0[r] + bb0, 0.f);
        out[g * OUTn + o1] = fmaxf(acc1[r] + bb1, 0.f);
    }
}

extern "C" void kernel_launch(void* const* d_in, const int* in_sizes, int n_in,
                              void* d_out, int out_size, void* d_ws, size_t ws_size,
                              hipStream_t stream) {
    const float* x = (const float*)d_in[0];
    const int* edge = (const int*)d_in[1];
    const float* W = (const float*)d_in[2];
    const float* bias = (const float*)d_in[3];
    float* out = (float*)d_out;
    unsigned short* Wb = (unsigned short*)d_ws;   // 64 KB

    build_wb<<<16, 256, 0, stream>>>(W, Wb);
    mrconv_kernel<<<2560, 256, 0, stream>>>(x, edge, Wb, bias, out);
}

// Round 2
// 113.097 us; speedup vs baseline: 1.1272x; 1.1272x over previous
//
#include <hip/hip_runtime.h>

// MRConv1d: B=4, N=10000, C=128, K=16, OUT=128
// out[b,n,o] = relu( sum_c2 feat[b,n,c2]*W[o,c2] + bias[o] )
// feat[b,n,2c]   = x[b,n,c]
// feat[b,n,2c+1] = max_k( x[b, e0[b,n,k], c] - x[b, e1[b,n,k], c] )

#define Bn 4
#define Nn 10000
#define Cn 128
#define Kn 16
#define OUTn 128
#define Mn 16           // nodes per block
#define FPAD 8          // sfeat row pad in bf16 elems (row = 264 ushorts = 528 B, 16B-aligned)

typedef __attribute__((ext_vector_type(8))) short short8;
typedef __attribute__((ext_vector_type(4))) float floatx4;

__device__ __forceinline__ unsigned short f2bf(float f) {
    union { float f; unsigned u; } v; v.f = f;
    unsigned r = v.u + 0x7fffu + ((v.u >> 16) & 1u);   // RNE
    return (unsigned short)(r >> 16);
}

// Pack W [OUT, 2C] fp32 into bf16 B-fragments for mfma_f32_16x16x32_bf16.
// Wb[((tile*8 + step)*64 + lane)*8 + j] = bf16(W[o][c2])
//   with o = tile*16 + (lane&15), c2 = step*32 + (lane>>4)*8 + j.
__global__ __launch_bounds__(256) void build_wb(const float* __restrict__ W,
                                                unsigned short* __restrict__ Wb) {
    int tid = blockIdx.x * 256 + threadIdx.x;   // 0..4095
    int lane = tid & 63;
    int step = (tid >> 6) & 7;
    int tile = tid >> 9;
    int o = tile * 16 + (lane & 15);
    int quad = lane >> 4;
    unsigned short v[8];
#pragma unroll
    for (int j = 0; j < 8; ++j) {
        int c2 = step * 32 + quad * 8 + j;
        v[j] = f2bf(W[o * (2 * Cn) + c2]);
    }
    uint4 pk;
    pk.x = (unsigned)v[0] | ((unsigned)v[1] << 16);
    pk.y = (unsigned)v[2] | ((unsigned)v[3] << 16);
    pk.z = (unsigned)v[4] | ((unsigned)v[5] << 16);
    pk.w = (unsigned)v[6] | ((unsigned)v[7] << 16);
    *(uint4*)(Wb + (size_t)tid * 8) = pk;
}

__global__ __launch_bounds__(256) void mrconv_kernel(
    const float* __restrict__ x, const int* __restrict__ edge,
    const unsigned short* __restrict__ Wb, const float* __restrict__ bias,
    float* __restrict__ out)
{
    __shared__ unsigned short sfeat[Mn][2 * Cn + FPAD];  // bf16 feature tile, interleaved
    __shared__ int sidx[2][Mn][Kn];

    // XCD-aware mapping: batch b pinned to XCD slots {b, b+4} so each XCD's
    // 4MiB L2 mostly serves one 5.1MB batch slice of x.
    int bi = blockIdx.x;
    int slot = bi & 7;
    int b = slot & 3;
    int nb = (bi >> 3) * 2 + (slot >> 2);
    if (nb >= Nn / Mn) return;
    const int n0 = nb * Mn;
    const int gbase = b * Nn + n0;

    const int t = threadIdx.x;
    const int wv = t >> 6;      // wave 0..3
    const int lane = t & 63;

    // stage edge indices for the block's 16 nodes: 2*16*16 = 512 ints
    for (int i = t; i < 2 * Mn * Kn; i += 256) {
        int s = i >> 8;
        int m = (i >> 4) & 15;
        int k = i & 15;
        sidx[s][m][k] = edge[s * (Bn * Nn * Kn) + (gbase + m) * Kn + k];
    }
    __syncthreads();

    const float* xb = x + b * (Nn * Cn);

    // phase 1: gather + max-relative.
    // Half-wave per node: 32 lanes x float4 = 128 channels. Wave covers 2 nodes
    // at once; k chunked by 8 -> 16 float4 loads (16KB/wave) in flight.
    const int half = lane >> 5;
    const int ch = 4 * (lane & 31);   // first of 4 channels for this lane
    for (int pr = 0; pr < 2; ++pr) {
        const int m = wv * 4 + pr * 2 + half;
        const float4 xs = *(const float4*)(xb + (n0 + m) * Cn + ch);
        float4 r = {-3.402823466e+38f, -3.402823466e+38f,
                    -3.402823466e+38f, -3.402823466e+38f};
#pragma unroll
        for (int kc = 0; kc < 2; ++kc) {
            float4 vj[8], vi[8];
#pragma unroll
            for (int u = 0; u < 8; ++u) {
                const int jj = sidx[0][m][kc * 8 + u];
                const int ii = sidx[1][m][kc * 8 + u];
                vj[u] = *(const float4*)(xb + jj * Cn + ch);
                vi[u] = *(const float4*)(xb + ii * Cn + ch);
            }
#pragma unroll
            for (int u = 0; u < 8; ++u) {
                r.x = fmaxf(r.x, vj[u].x - vi[u].x);
                r.y = fmaxf(r.y, vj[u].y - vi[u].y);
                r.z = fmaxf(r.z, vj[u].z - vi[u].z);
                r.w = fmaxf(r.w, vj[u].w - vi[u].w);
            }
        }
        // interleaved bf16: positions 2ch.. : {x0,rel0,x1,rel1,x2,rel2,x3,rel3}
        uint4 pk;
        pk.x = (unsigned)f2bf(xs.x) | ((unsigned)f2bf(r.x) << 16);
        pk.y = (unsigned)f2bf(xs.y) | ((unsigned)f2bf(r.y) << 16);
        pk.z = (unsigned)f2bf(xs.z) | ((unsigned)f2bf(r.z) << 16);
        pk.w = (unsigned)f2bf(xs.w) | ((unsigned)f2bf(r.w) << 16);
        *(uint4*)&sfeat[m][2 * ch] = pk;
    }
    __syncthreads();

    // phase 2: out_tile[16 nodes][128] = feat[16][256] @ Wt[256][128] via MFMA bf16.
    const int m16 = lane & 15;
    const int quad = lane >> 4;
    floatx4 acc0 = {0.f, 0.f, 0.f, 0.f};
    floatx4 acc1 = {0.f, 0.f, 0.f, 0.f};
    const short8* wb8 = (const short8*)Wb;
    const int tile0 = 2 * wv, tile1 = 2 * wv + 1;
#pragma unroll
    for (int step = 0; step < 8; ++step) {
        short8 a = *(const short8*)&sfeat[m16][step * 32 + quad * 8];
        short8 b0 = wb8[(tile0 * 8 + step) * 64 + lane];
        short8 b1 = wb8[(tile1 * 8 + step) * 64 + lane];
        acc0 = __builtin_amdgcn_mfma_f32_16x16x32_bf16(a, b0, acc0, 0, 0, 0);
        acc1 = __builtin_amdgcn_mfma_f32_16x16x32_bf16(a, b1, acc1, 0, 0, 0);
    }
    // C/D layout: col = lane&15, row = quad*4 + reg
    const int o0 = tile0 * 16 + m16;
    const int o1 = tile1 * 16 + m16;
    const float bb0 = bias[o0], bb1 = bias[o1];
#pragma unroll
    for (int r = 0; r < 4; ++r) {
        int g = gbase + quad * 4 + r;
        out[g * OUTn + o0] = fmaxf(acc0[r] + bb0, 0.f);
        out[g * OUTn + o1] = fmaxf(acc1[r] + bb1, 0.f);
    }
}

extern "C" void kernel_launch(void* const* d_in, const int* in_sizes, int n_in,
                              void* d_out, int out_size, void* d_ws, size_t ws_size,
                              hipStream_t stream) {
    const float* x = (const float*)d_in[0];
    const int* edge = (const int*)d_in[1];
    const float* W = (const float*)d_in[2];
    const float* bias = (const float*)d_in[3];
    float* out = (float*)d_out;
    unsigned short* Wb = (unsigned short*)d_ws;   // 64 KB

    build_wb<<<16, 256, 0, stream>>>(W, Wb);
    mrconv_kernel<<<2560, 256, 0, stream>>>(x, edge, Wb, bias, out);
}

// Round 3
// 101.575 us; speedup vs baseline: 1.2551x; 1.1134x over previous
//
#include <hip/hip_runtime.h>

// MRConv1d: B=4, N=10000, C=128, K=16, OUT=128
// out[b,n,o] = relu( sum_c2 feat[b,n,c2]*W[o,c2] + bias[o] )
// feat[b,n,2c]   = x[b,n,c]
// feat[b,n,2c+1] = max_k( x[b, e0[b,n,k], c] - x[b, e1[b,n,k], c] )
//
// R3 strategy: pre-convert x to bf16 (10.2 MB; 2.56 MB/batch slice fits the
// 4 MiB per-XCD L2) -> gather traffic halves and L2 misses vanish.

#define Bn 4
#define Nn 10000
#define Cn 128
#define Kn 16
#define OUTn 128
#define Mn 16           // nodes per block
#define FPAD 8          // sfeat row pad (row = 264 ushorts = 528 B)

typedef __attribute__((ext_vector_type(8))) short short8;
typedef __attribute__((ext_vector_type(4))) float floatx4;

__device__ __forceinline__ unsigned short f2bf(float f) {
    union { float f; unsigned u; } v; v.f = f;
    unsigned r = v.u + 0x7fffu + ((v.u >> 16) & 1u);   // RNE
    return (unsigned short)(r >> 16);
}
__device__ __forceinline__ float bf2f(unsigned short h) {
    union { unsigned u; float f; } v; v.u = ((unsigned)h) << 16;
    return v.f;
}

// x fp32 -> bf16, 8 floats per thread. 4*10000*128 = 5,120,000 floats.
__global__ __launch_bounds__(256) void convert_x(const float* __restrict__ x,
                                                 unsigned short* __restrict__ xh) {
    int i = blockIdx.x * 256 + threadIdx.x;      // 0..639999
    const float4* x4 = (const float4*)x;
    float4 a = x4[2 * i];
    float4 c = x4[2 * i + 1];
    uint4 pk;
    pk.x = (unsigned)f2bf(a.x) | ((unsigned)f2bf(a.y) << 16);
    pk.y = (unsigned)f2bf(a.z) | ((unsigned)f2bf(a.w) << 16);
    pk.z = (unsigned)f2bf(c.x) | ((unsigned)f2bf(c.y) << 16);
    pk.w = (unsigned)f2bf(c.z) | ((unsigned)f2bf(c.w) << 16);
    *(uint4*)(xh + 8 * (size_t)i) = pk;
}

// Pack W [OUT, 2C] fp32 into bf16 B-fragments for mfma_f32_16x16x32_bf16.
// Wb[((tile*8 + step)*64 + lane)*8 + j] = bf16(W[o][c2])
//   with o = tile*16 + (lane&15), c2 = step*32 + (lane>>4)*8 + j.
__global__ __launch_bounds__(256) void build_wb(const float* __restrict__ W,
                                                unsigned short* __restrict__ Wb) {
    int tid = blockIdx.x * 256 + threadIdx.x;   // 0..4095
    int lane = tid & 63;
    int step = (tid >> 6) & 7;
    int tile = tid >> 9;
    int o = tile * 16 + (lane & 15);
    int quad = lane >> 4;
    unsigned short v[8];
#pragma unroll
    for (int j = 0; j < 8; ++j) {
        int c2 = step * 32 + quad * 8 + j;
        v[j] = f2bf(W[o * (2 * Cn) + c2]);
    }
    uint4 pk;
    pk.x = (unsigned)v[0] | ((unsigned)v[1] << 16);
    pk.y = (unsigned)v[2] | ((unsigned)v[3] << 16);
    pk.z = (unsigned)v[4] | ((unsigned)v[5] << 16);
    pk.w = (unsigned)v[6] | ((unsigned)v[7] << 16);
    *(uint4*)(Wb + (size_t)tid * 8) = pk;
}

__global__ __launch_bounds__(256) void mrconv_kernel(
    const unsigned short* __restrict__ xh, const int* __restrict__ edge,
    const unsigned short* __restrict__ Wb, const float* __restrict__ bias,
    float* __restrict__ out)
{
    __shared__ unsigned short sfeat[Mn][2 * Cn + FPAD];  // bf16 feature tile, interleaved
    __shared__ int sidx[2][Mn][Kn];

    // XCD-aware mapping: batch b pinned to XCD slots {b, b+4}; each XCD's L2
    // serves one 2.56 MB bf16 batch slice (fits 4 MiB).
    int bi = blockIdx.x;
    int slot = bi & 7;
    int b = slot & 3;
    int nb = (bi >> 3) * 2 + (slot >> 2);
    if (nb >= Nn / Mn) return;
    const int n0 = nb * Mn;
    const int gbase = b * Nn + n0;

    const int t = threadIdx.x;
    const int wv = t >> 6;      // wave 0..3
    const int lane = t & 63;

    // stage edge indices for the block's 16 nodes: 2*16*16 = 512 ints
    for (int i = t; i < 2 * Mn * Kn; i += 256) {
        int s = i >> 8;
        int m = (i >> 4) & 15;
        int k = i & 15;
        sidx[s][m][k] = edge[s * (Bn * Nn * Kn) + (gbase + m) * Kn + k];
    }
    __syncthreads();

    const unsigned short* xbb = xh + (size_t)b * Nn * Cn;

    // phase 1: gather + max-relative in bf16.
    // Quarter-wave per row: 16 lanes x short8 (16 B) = 256 B row. Wave covers
    // 4 nodes simultaneously; k chunked by 8 -> 16 loads (16 KB/wave) in flight.
    {
        const int q = lane >> 4;          // quarter 0..3
        const int l16 = lane & 15;
        const int m = wv * 4 + q;         // node 0..15
        const int ch = l16 * 8;           // 8 channels per lane
        const short8 xs = *(const short8*)(xbb + (n0 + m) * Cn + ch);
        float r[8];
#pragma unroll
        for (int e = 0; e < 8; ++e) r[e] = -3.402823466e+38f;
#pragma unroll
        for (int kc = 0; kc < 2; ++kc) {
            short8 vj[8], vi[8];
#pragma unroll
            for (int u = 0; u < 8; ++u) {
                const int jj = sidx[0][m][kc * 8 + u];
                const int ii = sidx[1][m][kc * 8 + u];
                vj[u] = *(const short8*)(xbb + jj * Cn + ch);
                vi[u] = *(const short8*)(xbb + ii * Cn + ch);
            }
#pragma unroll
            for (int u = 0; u < 8; ++u) {
#pragma unroll
                for (int e = 0; e < 8; ++e) {
                    r[e] = fmaxf(r[e], bf2f((unsigned short)vj[u][e]) -
                                       bf2f((unsigned short)vi[u][e]));
                }
            }
        }
        // interleaved bf16 row: {x_c, rel_c} pairs; lane covers c in [ch, ch+8)
        uint4 pk0, pk1;
        pk0.x = (unsigned short)xs[0] | ((unsigned)f2bf(r[0]) << 16);
        pk0.y = (unsigned short)xs[1] | ((unsigned)f2bf(r[1]) << 16);
        pk0.z = (unsigned short)xs[2] | ((unsigned)f2bf(r[2]) << 16);
        pk0.w = (unsigned short)xs[3] | ((unsigned)f2bf(r[3]) << 16);
        pk1.x = (unsigned short)xs[4] | ((unsigned)f2bf(r[4]) << 16);
        pk1.y = (unsigned short)xs[5] | ((unsigned)f2bf(r[5]) << 16);
        pk1.z = (unsigned short)xs[6] | ((unsigned)f2bf(r[6]) << 16);
        pk1.w = (unsigned short)xs[7] | ((unsigned)f2bf(r[7]) << 16);
        *(uint4*)&sfeat[m][2 * ch] = pk0;
        *(uint4*)&sfeat[m][2 * ch + 8] = pk1;
    }
    __syncthreads();

    // phase 2: out_tile[16 nodes][128] = feat[16][256] @ Wt[256][128] via MFMA bf16.
    const int m16 = lane & 15;
    const int quad = lane >> 4;
    floatx4 acc0 = {0.f, 0.f, 0.f, 0.f};
    floatx4 acc1 = {0.f, 0.f, 0.f, 0.f};
    const short8* wb8 = (const short8*)Wb;
    const int tile0 = 2 * wv, tile1 = 2 * wv + 1;
#pragma unroll
    for (int step = 0; step < 8; ++step) {
        short8 a = *(const short8*)&sfeat[m16][step * 32 + quad * 8];
        short8 b0 = wb8[(tile0 * 8 + step) * 64 + lane];
        short8 b1 = wb8[(tile1 * 8 + step) * 64 + lane];
        acc0 = __builtin_amdgcn_mfma_f32_16x16x32_bf16(a, b0, acc0, 0, 0, 0);
        acc1 = __builtin_amdgcn_mfma_f32_16x16x32_bf16(a, b1, acc1, 0, 0, 0);
    }
    // C/D layout: col = lane&15, row = quad*4 + reg
    const int o0 = tile0 * 16 + m16;
    const int o1 = tile1 * 16 + m16;
    const float bb0 = bias[o0], bb1 = bias[o1];
#pragma unroll
    for (int r = 0; r < 4; ++r) {
        int g = gbase + quad * 4 + r;
        out[g * OUTn + o0] = fmaxf(acc0[r] + bb0, 0.f);
        out[g * OUTn + o1] = fmaxf(acc1[r] + bb1, 0.f);
    }
}

extern "C" void kernel_launch(void* const* d_in, const int* in_sizes, int n_in,
                              void* d_out, int out_size, void* d_ws, size_t ws_size,
                              hipStream_t stream) {
    const float* x = (const float*)d_in[0];
    const int* edge = (const int*)d_in[1];
    const float* W = (const float*)d_in[2];
    const float* bias = (const float*)d_in[3];
    float* out = (float*)d_out;

    unsigned short* Wb = (unsigned short*)d_ws;                  // 64 KB
    unsigned short* xh = (unsigned short*)((char*)d_ws + 65536); // 10.24 MB

    build_wb<<<16, 256, 0, stream>>>(W, Wb);
    convert_x<<<2500, 256, 0, stream>>>(x, xh);
    mrconv_kernel<<<2560, 256, 0, stream>>>(xh, edge, Wb, bias, out);
}